// Round 9
// baseline (211.939 us; speedup 1.0000x reference)
//
#include <hip/hip_runtime.h>

#define EMBED   1024
#define NHEADS  16
#define RANK    32
#define HDIM    64
#define BATCH   2
#define SEQ     2048
#define BSQ     (BATCH * SEQ)          // 4096 rows
#define CEXP    0.25505998f            // (1/sqrt(32)) * log2(e)

typedef __attribute__((ext_vector_type(8))) short bf16x8;   // 8 bf16 = 4 VGPRs
typedef __attribute__((ext_vector_type(4))) float f32x4;    // MFMA 16x16 acc

__device__ __forceinline__ float bf2f(unsigned short u) {
    union { unsigned int i; float f; } x; x.i = ((unsigned int)u) << 16;
    return x.f;
}
__device__ __forceinline__ unsigned short f2bf(float f) {
    union { float f; unsigned int i; } x; x.f = f;
    unsigned int r = x.i + 0x7FFFu + ((x.i >> 16) & 1u);    // RNE
    return (unsigned short)(r >> 16);
}

// async 16B/lane global->LDS copy; lptr wave-uniform (lane scatters +lane*16B)
#define ASYNC16(gp, lp) \
    __builtin_amdgcn_global_load_lds( \
        (const __attribute__((address_space(1))) void*)(gp), \
        (__attribute__((address_space(3))) void*)(lp), 16, 0, 0)

// ---------- merged prep: hs cvt + weight transposes + bias concat ----------
__global__ __launch_bounds__(256) void prep_all(
    const float* __restrict__ hs,
    const float* __restrict__ Wq, const float* __restrict__ Wk,
    const float* __restrict__ Wv, const float* __restrict__ Wo,
    const float* __restrict__ bq, const float* __restrict__ bk,
    const float* __restrict__ bv,
    unsigned short* __restrict__ hsb, unsigned short* __restrict__ wT_all,
    unsigned short* __restrict__ woT, float* __restrict__ ball)
{
    __shared__ float L[64][65];
    const int blk = blockIdx.x;
    const int t = threadIdx.x;

    if (blk < 2048) {
        const size_t i = ((size_t)blk * 256 + t) * 8;
        float4 v0 = *(const float4*)(hs + i);
        float4 v1 = *(const float4*)(hs + i + 4);
        ushort4 o0, o1;
        o0.x = f2bf(v0.x); o0.y = f2bf(v0.y); o0.z = f2bf(v0.z); o0.w = f2bf(v0.w);
        o1.x = f2bf(v1.x); o1.y = f2bf(v1.y); o1.z = f2bf(v1.z); o1.w = f2bf(v1.w);
        *(ushort4*)(hsb + i) = o0;
        *(ushort4*)(hsb + i + 4) = o1;
        return;
    }
    if (blk < 2816) {
        int idx = blk - 2048;
        int z, bx, by;
        if (idx < 256) { z = idx >> 7; int r2 = idx & 127; bx = r2 & 7; by = r2 >> 3; }
        else { idx -= 256; z = 2 + (idx >> 8); int r2 = idx & 255; bx = r2 & 15; by = r2 >> 4; }
        const int Nw = (z < 2) ? 512 : 1024;
        const float* W = (z == 0) ? Wq : (z == 1) ? Wk : (z == 2) ? Wv : Wo;
        unsigned short* dst = (z == 3) ? woT : (wT_all + (size_t)z * 512 * 1024);

        const int r = t >> 2, c0 = (t & 3) * 16;
        const float* src = W + (size_t)(by * 64 + r) * Nw + bx * 64 + c0;
        #pragma unroll
        for (int u = 0; u < 4; u++)
            *(float4*)&L[r][c0 + 4 * u] = *(const float4*)(src + 4 * u);
        __syncthreads();
        unsigned short* drow = dst + (size_t)(bx * 64 + r) * 1024 + by * 64 + c0;
        #pragma unroll
        for (int u4 = 0; u4 < 4; u4++) {
            ushort4 o;
            o.x = f2bf(L[c0 + 4 * u4 + 0][r]);
            o.y = f2bf(L[c0 + 4 * u4 + 1][r]);
            o.z = f2bf(L[c0 + 4 * u4 + 2][r]);
            o.w = f2bf(L[c0 + 4 * u4 + 3][r]);
            *(ushort4*)(drow + 4 * u4) = o;
        }
        return;
    }
    {
        const int i = (blk - 2816) * 256 + t;
        ball[i] = (i < 512) ? bq[i] : (i < 1024) ? bk[i - 512] : bv[i - 1024];
    }
}

// ---------- QKV MFMA GEMM: [4096][2048] = hsb @ wT^T + bias ----------
// 128x128 tile, BK=32, global_load_lds staging. Epilogue scatters to
// qH[bh][s][32], kH[bh][s][32], vT[bh*64+d][s].
__global__ __launch_bounds__(256) void gemm_qkv(
    const unsigned short* __restrict__ A, const unsigned short* __restrict__ BT,
    const float* __restrict__ bias,
    unsigned short* __restrict__ qH, unsigned short* __restrict__ kH,
    unsigned short* __restrict__ vTout)
{
    __shared__ unsigned short As[128 * 32];
    __shared__ unsigned short Bs[128 * 32];
    const int K = 1024;
    const int t = threadIdx.x;
    const int lane = t & 63;
    const int li = lane & 15, la = lane >> 4;
    const int w = t >> 6, wm = w >> 1, wn = w & 1;
    const int row0 = blockIdx.y * 128, col0 = blockIdx.x * 128;

    const int sr = lane >> 2, sc2 = (lane & 3) * 8;
    const unsigned short* ag0 = A + (size_t)(row0 + w * 32 + sr) * K + sc2;
    const unsigned short* ag1 = A + (size_t)(row0 + w * 32 + 16 + sr) * K + sc2;
    const unsigned short* bg0 = BT + (size_t)(col0 + w * 32 + sr) * K + sc2;
    const unsigned short* bg1 = BT + (size_t)(col0 + w * 32 + 16 + sr) * K + sc2;
    unsigned short* lA0 = &As[(w * 32) * 32];
    unsigned short* lA1 = &As[(w * 32 + 16) * 32];
    unsigned short* lB0 = &Bs[(w * 32) * 32];
    unsigned short* lB1 = &Bs[(w * 32 + 16) * 32];

    f32x4 acc[4][4];
    #pragma unroll
    for (int i = 0; i < 4; i++)
        #pragma unroll
        for (int j = 0; j < 4; j++)
            acc[i][j] = (f32x4){0.f, 0.f, 0.f, 0.f};

    for (int k0 = 0; k0 < K; k0 += 32) {
        ASYNC16(ag0 + k0, lA0);
        ASYNC16(ag1 + k0, lA1);
        ASYNC16(bg0 + k0, lB0);
        ASYNC16(bg1 + k0, lB1);
        __syncthreads();
        bf16x8 af[4], bfr[4];
        #pragma unroll
        for (int mt = 0; mt < 4; mt++)
            af[mt] = *(const bf16x8*)&As[(wm * 64 + mt * 16 + li) * 32 + la * 8];
        #pragma unroll
        for (int nt = 0; nt < 4; nt++)
            bfr[nt] = *(const bf16x8*)&Bs[(wn * 64 + nt * 16 + li) * 32 + la * 8];
        #pragma unroll
        for (int mt = 0; mt < 4; mt++)
            #pragma unroll
            for (int nt = 0; nt < 4; nt++)
                acc[mt][nt] = __builtin_amdgcn_mfma_f32_16x16x32_bf16(af[mt], bfr[nt], acc[mt][nt], 0, 0, 0);
        __syncthreads();
    }

    const int bb = row0 >> 11;               // batch (tile never crosses)
    const int jb = (row0 & 2047) + wm * 64;
    #pragma unroll
    for (int nt = 0; nt < 4; nt++) {
        const int col = col0 + wn * 64 + nt * 16 + li;
        const float bval = bias[col];
        if (col < 1024) {
            const int hh = (col & 511) >> 5;
            const int rr = col & 31;
            unsigned short* base = ((col < 512) ? qH : kH)
                + ((size_t)(bb * 16 + hh) * 2048) * 32 + rr;
            #pragma unroll
            for (int mt = 0; mt < 4; mt++)
                #pragma unroll
                for (int r = 0; r < 4; r++)
                    base[(size_t)(jb + mt * 16 + la * 4 + r) * 32] =
                        f2bf(acc[mt][nt][r] + bval);
        } else {
            const int hd = col - 1024;
            unsigned short* dcol = vTout + ((size_t)(bb * 16 + (hd >> 6)) * 64 + (hd & 63)) * SEQ;
            #pragma unroll
            for (int mt = 0; mt < 4; mt++) {
                const int srow = jb + mt * 16 + la * 4;
                ushort4 o;
                o.x = f2bf(acc[mt][nt][0] + bval);
                o.y = f2bf(acc[mt][nt][1] + bval);
                o.z = f2bf(acc[mt][nt][2] + bval);
                o.w = f2bf(acc[mt][nt][3] + bval);
                *(ushort4*)(dcol + srow) = o;
            }
        }
    }
}

// ---------- out-proj GEMM: d_out[4096][1024] f32 = ao @ woT^T + bo ----------
// BM=64, BN=128 -> 512 blocks (2/CU). 4 waves 2x2, wave tile 32x64.
__global__ __launch_bounds__(256) void gemm_out(
    const unsigned short* __restrict__ A, const unsigned short* __restrict__ BT,
    const float* __restrict__ bias, float* __restrict__ C)
{
    __shared__ unsigned short As[64 * 32];
    __shared__ unsigned short Bs[128 * 32];
    const int K = 1024;
    const int t = threadIdx.x;
    const int lane = t & 63;
    const int li = lane & 15, la = lane >> 4;
    const int w = t >> 6, wm = w >> 1, wn = w & 1;
    const int row0 = blockIdx.y * 64, col0 = blockIdx.x * 128;

    const int sr = lane >> 2, sc2 = (lane & 3) * 8;
    const unsigned short* ag0 = A + (size_t)(row0 + w * 16 + sr) * K + sc2;
    const unsigned short* bg0 = BT + (size_t)(col0 + w * 32 + sr) * K + sc2;
    const unsigned short* bg1 = BT + (size_t)(col0 + w * 32 + 16 + sr) * K + sc2;
    unsigned short* lA0 = &As[(w * 16) * 32];
    unsigned short* lB0 = &Bs[(w * 32) * 32];
    unsigned short* lB1 = &Bs[(w * 32 + 16) * 32];

    f32x4 acc[2][4];
    #pragma unroll
    for (int i = 0; i < 2; i++)
        #pragma unroll
        for (int j = 0; j < 4; j++)
            acc[i][j] = (f32x4){0.f, 0.f, 0.f, 0.f};

    for (int k0 = 0; k0 < K; k0 += 32) {
        ASYNC16(ag0 + k0, lA0);
        ASYNC16(bg0 + k0, lB0);
        ASYNC16(bg1 + k0, lB1);
        __syncthreads();
        bf16x8 af[2], bfr[4];
        #pragma unroll
        for (int mt = 0; mt < 2; mt++)
            af[mt] = *(const bf16x8*)&As[(wm * 32 + mt * 16 + li) * 32 + la * 8];
        #pragma unroll
        for (int nt = 0; nt < 4; nt++)
            bfr[nt] = *(const bf16x8*)&Bs[(wn * 64 + nt * 16 + li) * 32 + la * 8];
        #pragma unroll
        for (int mt = 0; mt < 2; mt++)
            #pragma unroll
            for (int nt = 0; nt < 4; nt++)
                acc[mt][nt] = __builtin_amdgcn_mfma_f32_16x16x32_bf16(af[mt], bfr[nt], acc[mt][nt], 0, 0, 0);
        __syncthreads();
    }

    #pragma unroll
    for (int nt = 0; nt < 4; nt++) {
        const int col = col0 + wn * 64 + nt * 16 + li;
        const float bval = bias[col];
        #pragma unroll
        for (int mt = 0; mt < 2; mt++)
            #pragma unroll
            for (int r = 0; r < 4; r++) {
                const int row = row0 + wm * 32 + mt * 16 + la * 4 + r;
                C[(size_t)row * 1024 + col] = acc[mt][nt][r] + bval;
            }
    }
}

// ---------- MFMA flash attention v5: j split across waves ----------
// 2048 blocks (blockIdx = itile*32 + bh -> per-head XCD locality).
// Wave w owns j-slice [j0+w*32, +32) each iter (j0 += 128). K/V frags loaded
// DIRECTLY from global (coalesced, no duplication). S^T C-layout -> per-wave
// private LDS P bounce (stride 40, conflict-free, no in-loop barriers).
// l via ones-vector MFMA (row-sum). End: LDS cross-wave O/l reduction.
__global__ __launch_bounds__(256, 3) void attn_v5(
    const unsigned short* __restrict__ qH,
    const unsigned short* __restrict__ kH,
    const unsigned short* __restrict__ vT,
    unsigned short* __restrict__ ao)
{
    __shared__ float smem[2688];                  // 10752 B
    unsigned short* P = (unsigned short*)smem;    // per-wave [32][40] shorts
    float* lbuf = smem + 2560;                    // [4][32] f32

    const int t = threadIdx.x;
    const int lane = t & 63;
    const int li = lane & 15, la = lane >> 4;
    const int w = t >> 6;

    const int bh = blockIdx.x & 31;
    const int itile = blockIdx.x >> 5;
    const int i0 = itile * 32;
    const int b = bh >> 4, h = bh & 15;

    // Q frags (B-operand: n=i=li, k=r=la*8..+7), CEXP folded
    bf16x8 qf[2];
    #pragma unroll
    for (int it = 0; it < 2; it++) {
        const unsigned short* qp = qH + ((size_t)bh * 2048 + i0 + it * 16 + li) * 32 + la * 8;
        ushort4 q0 = *(const ushort4*)qp;
        ushort4 q1 = *(const ushort4*)(qp + 4);
        short u[8];
        u[0] = (short)f2bf(bf2f(q0.x) * CEXP);
        u[1] = (short)f2bf(bf2f(q0.y) * CEXP);
        u[2] = (short)f2bf(bf2f(q0.z) * CEXP);
        u[3] = (short)f2bf(bf2f(q0.w) * CEXP);
        u[4] = (short)f2bf(bf2f(q1.x) * CEXP);
        u[5] = (short)f2bf(bf2f(q1.y) * CEXP);
        u[6] = (short)f2bf(bf2f(q1.z) * CEXP);
        u[7] = (short)f2bf(bf2f(q1.w) * CEXP);
        qf[it] = *(const bf16x8*)u;
    }

    bf16x8 vones;
    #pragma unroll
    for (int u2 = 0; u2 < 8; u2++) vones[u2] = (short)0x3F80;   // bf16 1.0

    // K: row j = j0 + w*32 + jt*16 + li, cols la*8..+7  (contiguous 1KB/wave)
    const unsigned short* kbase = kH + (size_t)bh * 2048 * 32
                                  + (size_t)(w * 32 + li) * 32 + la * 8;
    // V: row d = dt*16+li, cols j0 + w*32 + la*8  (64B-line aligned per wave)
    const unsigned short* vbase = vT + (size_t)bh * 64 * SEQ
                                  + (size_t)li * SEQ + w * 32 + la * 8;

    unsigned short* Pw = P + w * 32 * 40;

    f32x4 accO[2][4], accl[2];
    #pragma unroll
    for (int mt = 0; mt < 2; mt++) {
        accl[mt] = (f32x4){0.f, 0.f, 0.f, 0.f};
        #pragma unroll
        for (int dt = 0; dt < 4; dt++) accO[mt][dt] = (f32x4){0.f, 0.f, 0.f, 0.f};
    }

    bf16x8 kf0 = *(const bf16x8*)(kbase);
    bf16x8 kf1 = *(const bf16x8*)(kbase + 512);

    for (int j0 = 0; j0 < SEQ; j0 += 128) {
        // V loads for this iter (issued early; consumed after QK+softmax)
        bf16x8 vf[4];
        #pragma unroll
        for (int dt = 0; dt < 4; dt++)
            vf[dt] = *(const bf16x8*)(vbase + (size_t)dt * 16 * SEQ + j0);
        // K prefetch for next iter
        const int jn = (j0 + 128) & 2047;
        const bf16x8 kn0 = *(const bf16x8*)(kbase + (size_t)jn * 32);
        const bf16x8 kn1 = *(const bf16x8*)(kbase + (size_t)jn * 32 + 512);

        // S^T = K·Q^T: D[m=j][n=i]; lane holds i=it*16+li, j=w32+jt*16+la*4+r
        f32x4 sc[2][2];
        sc[0][0] = __builtin_amdgcn_mfma_f32_16x16x32_bf16(kf0, qf[0], (f32x4){0.f,0.f,0.f,0.f}, 0, 0, 0);
        sc[0][1] = __builtin_amdgcn_mfma_f32_16x16x32_bf16(kf0, qf[1], (f32x4){0.f,0.f,0.f,0.f}, 0, 0, 0);
        sc[1][0] = __builtin_amdgcn_mfma_f32_16x16x32_bf16(kf1, qf[0], (f32x4){0.f,0.f,0.f,0.f}, 0, 0, 0);
        sc[1][1] = __builtin_amdgcn_mfma_f32_16x16x32_bf16(kf1, qf[1], (f32x4){0.f,0.f,0.f,0.f}, 0, 0, 0);

        // fixed-max softmax: p = 2^s; pack into P[i][j] (wave-private region)
        #pragma unroll
        for (int jt = 0; jt < 2; jt++)
            #pragma unroll
            for (int it = 0; it < 2; it++) {
                union { float f; unsigned int u; } c0, c1, c2, c3;
                c0.f = exp2f(sc[jt][it][0]);
                c1.f = exp2f(sc[jt][it][1]);
                c2.f = exp2f(sc[jt][it][2]);
                c3.f = exp2f(sc[jt][it][3]);
                uint2 pk;
                pk.x = __builtin_amdgcn_perm(c1.u + 0x8000u, c0.u + 0x8000u, 0x07060302u);
                pk.y = __builtin_amdgcn_perm(c3.u + 0x8000u, c2.u + 0x8000u, 0x07060302u);
                *(uint2*)&Pw[(it * 16 + li) * 40 + jt * 16 + la * 4] = pk;
            }

        // O += P·V over this wave's 32 j; l += P·1 (row-sum via MFMA)
        #pragma unroll
        for (int mt = 0; mt < 2; mt++) {
            const bf16x8 af = *(const bf16x8*)&Pw[(mt * 16 + li) * 40 + la * 8];
            accl[mt] = __builtin_amdgcn_mfma_f32_16x16x32_bf16(af, vones, accl[mt], 0, 0, 0);
            #pragma unroll
            for (int dt = 0; dt < 4; dt++)
                accO[mt][dt] = __builtin_amdgcn_mfma_f32_16x16x32_bf16(af, vf[dt], accO[mt][dt], 0, 0, 0);
        }
        kf0 = kn0; kf1 = kn1;
    }

    // ---- epilogue: cross-wave l and O reduction via LDS ----
    // accl: all n-cols identical; rows i = mt*16 + la*4 + r (this wave's j-sum)
    if (li == 0) {
        #pragma unroll
        for (int mt = 0; mt < 2; mt++) {
            float4 tv;
            tv.x = accl[mt][0]; tv.y = accl[mt][1];
            tv.z = accl[mt][2]; tv.w = accl[mt][3];
            *(float4*)&lbuf[w * 32 + mt * 16 + la * 4] = tv;
        }
    }
    __syncthreads();

    const int ir = w * 8 + (lane >> 3);     // this wave's output rows
    const int dl = (lane & 7) * 2;
    const float lsum = lbuf[ir] + lbuf[32 + ir] + lbuf[64 + ir] + lbuf[96 + ir];
    const float linv = 1.0f / lsum;
    float* obuf = smem;                      // reuse P region: per-wave [32][16]
    unsigned short* aorow = ao + ((size_t)(b * SEQ + i0 + ir)) * 1024 + h * 64 + dl;

    #pragma unroll
    for (int s = 0; s < 4; s++) {           // d-block stages
        float* ow = obuf + w * 512;
        #pragma unroll
        for (int mt = 0; mt < 2; mt++)
            #pragma unroll
            for (int r = 0; r < 4; r++)
                ow[(mt * 16 + la * 4 + r) * 16 + li] = accO[mt][s][r];
        __syncthreads();
        float v0 = 0.f, v1 = 0.f;
        #pragma unroll
        for (int w2 = 0; w2 < 4; w2++) {
            const float2 x = *(const float2*)&obuf[w2 * 512 + ir * 16 + dl];
            v0 += x.x; v1 += x.y;
        }
        const unsigned int outp = (unsigned int)f2bf(v0 * linv)
                                | ((unsigned int)f2bf(v1 * linv) << 16);
        *(unsigned int*)(aorow + s * 16) = outp;
        __syncthreads();
    }
}

extern "C" void kernel_launch(void* const* d_in, const int* in_sizes, int n_in,
                              void* d_out, int out_size, void* d_ws, size_t ws_size,
                              hipStream_t stream) {
    const float* hs = (const float*)d_in[0];
    const float* Wq = (const float*)d_in[1];
    const float* bq = (const float*)d_in[2];
    const float* Wk = (const float*)d_in[3];
    const float* bk = (const float*)d_in[4];
    const float* Wv = (const float*)d_in[5];
    const float* bv = (const float*)d_in[6];
    const float* Wo = (const float*)d_in[7];
    const float* bo = (const float*)d_in[8];

    char* p = (char*)d_ws;                                        // 38 MB total
    unsigned short* hsb = (unsigned short*)(p);                   //  8 MB
    unsigned short* wT  = (unsigned short*)(p + 8388608u);        //  4 MB
    unsigned short* woT = (unsigned short*)(p + 12582912u);       //  2 MB
    float*          ball= (float*)(p + 14680064u);                //  8 KB
    unsigned short* qHb = (unsigned short*)(p + 14688256u);       //  4 MB
    unsigned short* kHb = (unsigned short*)(p + 18882560u);       //  4 MB
    unsigned short* vTb = (unsigned short*)(p + 23076864u);       //  8 MB
    unsigned short* ao  = (unsigned short*)(p + 31465472u);       //  8 MB

    prep_all<<<dim3(2824), 256, 0, stream>>>(hs, Wq, Wk, Wv, Wo, bq, bk, bv,
                                             hsb, wT, woT, ball);

    gemm_qkv<<<dim3(16, 32), 256, 0, stream>>>(hsb, wT, ball, qHb, kHb, vTb);

    attn_v5<<<dim3(2048), 256, 0, stream>>>(qHb, kHb, vTb, ao);

    gemm_out<<<dim3(8, 64), 256, 0, stream>>>(ao, woT, bo, (float*)d_out);
}

// Round 10
// 198.612 us; speedup vs baseline: 1.0671x; 1.0671x over previous
//
#include <hip/hip_runtime.h>

#define EMBED   1024
#define NHEADS  16
#define RANK    32
#define HDIM    64
#define BATCH   2
#define SEQ     2048
#define BSQ     (BATCH * SEQ)          // 4096 rows
#define CEXP    0.25505998f            // (1/sqrt(32)) * log2(e)

typedef __attribute__((ext_vector_type(8))) short bf16x8;   // 8 bf16 = 4 VGPRs
typedef __attribute__((ext_vector_type(4))) float f32x4;    // MFMA 16x16 acc

__device__ __forceinline__ float bf2f(unsigned short u) {
    union { unsigned int i; float f; } x; x.i = ((unsigned int)u) << 16;
    return x.f;
}
__device__ __forceinline__ unsigned short f2bf(float f) {
    union { float f; unsigned int i; } x; x.f = f;
    unsigned int r = x.i + 0x7FFFu + ((x.i >> 16) & 1u);    // RNE
    return (unsigned short)(r >> 16);
}

// async 16B/lane global->LDS copy; lptr wave-uniform (lane scatters +lane*16B)
#define ASYNC16(gp, lp) \
    __builtin_amdgcn_global_load_lds( \
        (const __attribute__((address_space(1))) void*)(gp), \
        (__attribute__((address_space(3))) void*)(lp), 16, 0, 0)

// ---------- merged prep: hs cvt + weight transposes + bias concat ----------
__global__ __launch_bounds__(256) void prep_all(
    const float* __restrict__ hs,
    const float* __restrict__ Wq, const float* __restrict__ Wk,
    const float* __restrict__ Wv, const float* __restrict__ Wo,
    const float* __restrict__ bq, const float* __restrict__ bk,
    const float* __restrict__ bv,
    unsigned short* __restrict__ hsb, unsigned short* __restrict__ wT_all,
    unsigned short* __restrict__ woT, float* __restrict__ ball)
{
    __shared__ float L[64][65];
    const int blk = blockIdx.x;
    const int t = threadIdx.x;

    if (blk < 2048) {
        const size_t i = ((size_t)blk * 256 + t) * 8;
        float4 v0 = *(const float4*)(hs + i);
        float4 v1 = *(const float4*)(hs + i + 4);
        ushort4 o0, o1;
        o0.x = f2bf(v0.x); o0.y = f2bf(v0.y); o0.z = f2bf(v0.z); o0.w = f2bf(v0.w);
        o1.x = f2bf(v1.x); o1.y = f2bf(v1.y); o1.z = f2bf(v1.z); o1.w = f2bf(v1.w);
        *(ushort4*)(hsb + i) = o0;
        *(ushort4*)(hsb + i + 4) = o1;
        return;
    }
    if (blk < 2816) {
        int idx = blk - 2048;
        int z, bx, by;
        if (idx < 256) { z = idx >> 7; int r2 = idx & 127; bx = r2 & 7; by = r2 >> 3; }
        else { idx -= 256; z = 2 + (idx >> 8); int r2 = idx & 255; bx = r2 & 15; by = r2 >> 4; }
        const int Nw = (z < 2) ? 512 : 1024;
        const float* W = (z == 0) ? Wq : (z == 1) ? Wk : (z == 2) ? Wv : Wo;
        unsigned short* dst = (z == 3) ? woT : (wT_all + (size_t)z * 512 * 1024);

        const int r = t >> 2, c0 = (t & 3) * 16;
        const float* src = W + (size_t)(by * 64 + r) * Nw + bx * 64 + c0;
        #pragma unroll
        for (int u = 0; u < 4; u++)
            *(float4*)&L[r][c0 + 4 * u] = *(const float4*)(src + 4 * u);
        __syncthreads();
        unsigned short* drow = dst + (size_t)(bx * 64 + r) * 1024 + by * 64 + c0;
        #pragma unroll
        for (int u4 = 0; u4 < 4; u4++) {
            ushort4 o;
            o.x = f2bf(L[c0 + 4 * u4 + 0][r]);
            o.y = f2bf(L[c0 + 4 * u4 + 1][r]);
            o.z = f2bf(L[c0 + 4 * u4 + 2][r]);
            o.w = f2bf(L[c0 + 4 * u4 + 3][r]);
            *(ushort4*)(drow + 4 * u4) = o;
        }
        return;
    }
    {
        const int i = (blk - 2816) * 256 + t;
        ball[i] = (i < 512) ? bq[i] : (i < 1024) ? bk[i - 512] : bv[i - 1024];
    }
}

// ---------- QKV MFMA GEMM: [4096][2048] = hsb @ wT^T + bias ----------
// 128x128 tile, BK=32, global_load_lds staging. Epilogue scatters to
// qH[bh][s][32], kH[bh][s][32], vT[bh*64+d][s].
__global__ __launch_bounds__(256) void gemm_qkv(
    const unsigned short* __restrict__ A, const unsigned short* __restrict__ BT,
    const float* __restrict__ bias,
    unsigned short* __restrict__ qH, unsigned short* __restrict__ kH,
    unsigned short* __restrict__ vTout)
{
    __shared__ unsigned short As[128 * 32];
    __shared__ unsigned short Bs[128 * 32];
    const int K = 1024;
    const int t = threadIdx.x;
    const int lane = t & 63;
    const int li = lane & 15, la = lane >> 4;
    const int w = t >> 6, wm = w >> 1, wn = w & 1;
    const int row0 = blockIdx.y * 128, col0 = blockIdx.x * 128;

    const int sr = lane >> 2, sc2 = (lane & 3) * 8;
    const unsigned short* ag0 = A + (size_t)(row0 + w * 32 + sr) * K + sc2;
    const unsigned short* ag1 = A + (size_t)(row0 + w * 32 + 16 + sr) * K + sc2;
    const unsigned short* bg0 = BT + (size_t)(col0 + w * 32 + sr) * K + sc2;
    const unsigned short* bg1 = BT + (size_t)(col0 + w * 32 + 16 + sr) * K + sc2;
    unsigned short* lA0 = &As[(w * 32) * 32];
    unsigned short* lA1 = &As[(w * 32 + 16) * 32];
    unsigned short* lB0 = &Bs[(w * 32) * 32];
    unsigned short* lB1 = &Bs[(w * 32 + 16) * 32];

    f32x4 acc[4][4];
    #pragma unroll
    for (int i = 0; i < 4; i++)
        #pragma unroll
        for (int j = 0; j < 4; j++)
            acc[i][j] = (f32x4){0.f, 0.f, 0.f, 0.f};

    for (int k0 = 0; k0 < K; k0 += 32) {
        ASYNC16(ag0 + k0, lA0);
        ASYNC16(ag1 + k0, lA1);
        ASYNC16(bg0 + k0, lB0);
        ASYNC16(bg1 + k0, lB1);
        __syncthreads();
        bf16x8 af[4], bfr[4];
        #pragma unroll
        for (int mt = 0; mt < 4; mt++)
            af[mt] = *(const bf16x8*)&As[(wm * 64 + mt * 16 + li) * 32 + la * 8];
        #pragma unroll
        for (int nt = 0; nt < 4; nt++)
            bfr[nt] = *(const bf16x8*)&Bs[(wn * 64 + nt * 16 + li) * 32 + la * 8];
        #pragma unroll
        for (int mt = 0; mt < 4; mt++)
            #pragma unroll
            for (int nt = 0; nt < 4; nt++)
                acc[mt][nt] = __builtin_amdgcn_mfma_f32_16x16x32_bf16(af[mt], bfr[nt], acc[mt][nt], 0, 0, 0);
        __syncthreads();
    }

    const int bb = row0 >> 11;               // batch (tile never crosses)
    const int jb = (row0 & 2047) + wm * 64;
    #pragma unroll
    for (int nt = 0; nt < 4; nt++) {
        const int col = col0 + wn * 64 + nt * 16 + li;
        const float bval = bias[col];
        if (col < 1024) {
            const int hh = (col & 511) >> 5;
            const int rr = col & 31;
            unsigned short* base = ((col < 512) ? qH : kH)
                + ((size_t)(bb * 16 + hh) * 2048) * 32 + rr;
            #pragma unroll
            for (int mt = 0; mt < 4; mt++)
                #pragma unroll
                for (int r = 0; r < 4; r++)
                    base[(size_t)(jb + mt * 16 + la * 4 + r) * 32] =
                        f2bf(acc[mt][nt][r] + bval);
        } else {
            const int hd = col - 1024;
            unsigned short* dcol = vTout + ((size_t)(bb * 16 + (hd >> 6)) * 64 + (hd & 63)) * SEQ;
            #pragma unroll
            for (int mt = 0; mt < 4; mt++) {
                const int srow = jb + mt * 16 + la * 4;
                ushort4 o;
                o.x = f2bf(acc[mt][nt][0] + bval);
                o.y = f2bf(acc[mt][nt][1] + bval);
                o.z = f2bf(acc[mt][nt][2] + bval);
                o.w = f2bf(acc[mt][nt][3] + bval);
                *(ushort4*)(dcol + srow) = o;
            }
        }
    }
}

// ---------- out-proj GEMM: d_out[4096][1024] f32 = ao @ woT^T + bo ----------
__global__ __launch_bounds__(256) void gemm_out(
    const unsigned short* __restrict__ A, const unsigned short* __restrict__ BT,
    const float* __restrict__ bias, float* __restrict__ C)
{
    __shared__ unsigned short As[64 * 32];
    __shared__ unsigned short Bs[128 * 32];
    const int K = 1024;
    const int t = threadIdx.x;
    const int lane = t & 63;
    const int li = lane & 15, la = lane >> 4;
    const int w = t >> 6, wm = w >> 1, wn = w & 1;
    const int row0 = blockIdx.y * 64, col0 = blockIdx.x * 128;

    const int sr = lane >> 2, sc2 = (lane & 3) * 8;
    const unsigned short* ag0 = A + (size_t)(row0 + w * 16 + sr) * K + sc2;
    const unsigned short* bg0 = BT + (size_t)(col0 + w * 32 + sr) * K + sc2;
    const unsigned short* bg1 = BT + (size_t)(col0 + w * 32 + 16 + sr) * K + sc2;
    unsigned short* lA0 = &As[(w * 16) * 32];
    unsigned short* lB0 = &Bs[(w * 32) * 32];
    unsigned short* lB1 = &Bs[(w * 32 + 16) * 32];

    f32x4 acc[2][4];
    #pragma unroll
    for (int i = 0; i < 2; i++)
        #pragma unroll
        for (int j = 0; j < 4; j++)
            acc[i][j] = (f32x4){0.f, 0.f, 0.f, 0.f};

    for (int k0 = 0; k0 < K; k0 += 32) {
        ASYNC16(ag0 + k0, lA0);
        ASYNC16(bg0 + k0, lB0);
        ASYNC16(bg1 + k0, lB1);
        __syncthreads();
        bf16x8 af[2], bfr[4];
        #pragma unroll
        for (int mt = 0; mt < 2; mt++)
            af[mt] = *(const bf16x8*)&As[(wm * 32 + mt * 16 + li) * 32 + la * 8];
        #pragma unroll
        for (int nt = 0; nt < 4; nt++)
            bfr[nt] = *(const bf16x8*)&Bs[(wn * 64 + nt * 16 + li) * 32 + la * 8];
        #pragma unroll
        for (int mt = 0; mt < 2; mt++)
            #pragma unroll
            for (int nt = 0; nt < 4; nt++)
                acc[mt][nt] = __builtin_amdgcn_mfma_f32_16x16x32_bf16(af[mt], bfr[nt], acc[mt][nt], 0, 0, 0);
        __syncthreads();
    }

    #pragma unroll
    for (int nt = 0; nt < 4; nt++) {
        const int col = col0 + wn * 64 + nt * 16 + li;
        const float bval = bias[col];
        #pragma unroll
        for (int mt = 0; mt < 2; mt++)
            #pragma unroll
            for (int r = 0; r < 4; r++) {
                const int row = row0 + wm * 32 + mt * 16 + la * 4 + r;
                C[(size_t)row * 1024 + col] = acc[mt][nt][r] + bval;
            }
    }
}

// ---------- MFMA flash attention v6: i-tile 128, coop LDS staging ----------
// 512 blocks (blockIdx = itile*32 + bh -> XCD L2 locality, full j per block).
// Wave w owns i-rows [i0 + w*32, +32) (2 Q-frags -> 2x LDS frag reuse).
// Coop staging: K tile [64][48] (bank-balanced), V^T tile [64][72]; register
// prefetch of next tile. P bounce per-wave-private rows (no extra barriers).
// l accumulated via ones-vector MFMA -> same C-layout rows as O: epilogue
// needs no shuffles at all.
__global__ __launch_bounds__(256) void attn_v6(
    const unsigned short* __restrict__ qH,
    const unsigned short* __restrict__ kH,
    const unsigned short* __restrict__ vT,
    unsigned short* __restrict__ ao)
{
    __shared__ unsigned short kt[64 * 48];    // 6 KB   (stride 48: balanced)
    __shared__ unsigned short vt[64 * 72];    // 9 KB
    __shared__ unsigned short P[128 * 72];    // 18 KB

    const int t = threadIdx.x;
    const int lane = t & 63;
    const int li = lane & 15, la = lane >> 4;
    const int w = t >> 6;

    const int bh = blockIdx.x & 31;
    const int itile = blockIdx.x >> 5;
    const int i0 = itile * 128;
    const int b = bh >> 4, h = bh & 15;

    // 2 Q frags (B-operand: n=i, k=r), CEXP folded (loop-invariant)
    bf16x8 qf[2];
    #pragma unroll
    for (int it = 0; it < 2; it++) {
        const unsigned short* qp = qH + ((size_t)bh * 2048 + i0 + w * 32 + it * 16 + li) * 32 + la * 8;
        ushort4 q0 = *(const ushort4*)qp;
        ushort4 q1 = *(const ushort4*)(qp + 4);
        short u[8];
        u[0] = (short)f2bf(bf2f(q0.x) * CEXP);
        u[1] = (short)f2bf(bf2f(q0.y) * CEXP);
        u[2] = (short)f2bf(bf2f(q0.z) * CEXP);
        u[3] = (short)f2bf(bf2f(q0.w) * CEXP);
        u[4] = (short)f2bf(bf2f(q1.x) * CEXP);
        u[5] = (short)f2bf(bf2f(q1.y) * CEXP);
        u[6] = (short)f2bf(bf2f(q1.z) * CEXP);
        u[7] = (short)f2bf(bf2f(q1.w) * CEXP);
        qf[it] = *(const bf16x8*)u;
    }

    bf16x8 vones;
    #pragma unroll
    for (int u2 = 0; u2 < 8; u2++) vones[u2] = (short)0x3F80;   // bf16 1.0

    const unsigned short* kbase = kH + (size_t)bh * 2048 * 32;
    const unsigned short* vbase = vT + (size_t)bh * 64 * SEQ;

    // staging assignments
    const int kr = t >> 2, kc = (t & 3) * 8;        // K: 64 rows x 64B
    const int vr = t >> 3, vc = (t & 7) * 8;        // V: rows d / d+32, 128B runs

    f32x4 accO[2][4], accl[2];
    #pragma unroll
    for (int mt = 0; mt < 2; mt++) {
        accl[mt] = (f32x4){0.f, 0.f, 0.f, 0.f};
        #pragma unroll
        for (int dt = 0; dt < 4; dt++) accO[mt][dt] = (f32x4){0.f, 0.f, 0.f, 0.f};
    }

    // preload tile 0
    uint4 kreg  = *(const uint4*)(kbase + (size_t)kr * 32 + kc);
    uint4 vreg0 = *(const uint4*)(vbase + (size_t)vr * SEQ + vc);
    uint4 vreg1 = *(const uint4*)(vbase + (size_t)(vr + 32) * SEQ + vc);

    for (int j0 = 0; j0 < SEQ; j0 += 64) {
        __syncthreads();                       // prior iteration's frag reads done
        *(uint4*)&kt[kr * 48 + kc] = kreg;
        *(uint4*)&vt[vr * 72 + vc] = vreg0;
        *(uint4*)&vt[(vr + 32) * 72 + vc] = vreg1;
        __syncthreads();                       // staging visible

        // prefetch next tile (hidden under compute)
        const int jn = (j0 + 64) & 2047;
        kreg  = *(const uint4*)(kbase + (size_t)(jn + kr) * 32 + kc);
        vreg0 = *(const uint4*)(vbase + (size_t)vr * SEQ + jn + vc);
        vreg1 = *(const uint4*)(vbase + (size_t)(vr + 32) * SEQ + jn + vc);

        // S^T = K·Q^T: D[m=j][n=i]; each K-frag feeds 2 MFMAs (it=0,1)
        f32x4 sc[4][2];
        #pragma unroll
        for (int jt = 0; jt < 4; jt++) {
            const bf16x8 kf = *(const bf16x8*)&kt[(jt * 16 + li) * 48 + la * 8];
            sc[jt][0] = __builtin_amdgcn_mfma_f32_16x16x32_bf16(kf, qf[0], (f32x4){0.f,0.f,0.f,0.f}, 0, 0, 0);
            sc[jt][1] = __builtin_amdgcn_mfma_f32_16x16x32_bf16(kf, qf[1], (f32x4){0.f,0.f,0.f,0.f}, 0, 0, 0);
        }

        // fixed-max softmax: p = 2^s; pack pairs (+0x8000 then v_perm)
        #pragma unroll
        for (int jt = 0; jt < 4; jt++)
            #pragma unroll
            for (int it = 0; it < 2; it++) {
                union { float f; unsigned int u; } c0, c1, c2, c3;
                c0.f = exp2f(sc[jt][it][0]);
                c1.f = exp2f(sc[jt][it][1]);
                c2.f = exp2f(sc[jt][it][2]);
                c3.f = exp2f(sc[jt][it][3]);
                uint2 pk;
                pk.x = __builtin_amdgcn_perm(c1.u + 0x8000u, c0.u + 0x8000u, 0x07060302u);
                pk.y = __builtin_amdgcn_perm(c3.u + 0x8000u, c2.u + 0x8000u, 0x07060302u);
                *(uint2*)&P[(w * 32 + it * 16 + li) * 72 + jt * 16 + la * 4] = pk;
            }

        // O += P·V ; l += P·1  (P rows wave-private; lgkmcnt only, no barrier)
        #pragma unroll
        for (int mt = 0; mt < 2; mt++) {
            #pragma unroll
            for (int ks = 0; ks < 2; ks++) {
                const bf16x8 pf = *(const bf16x8*)&P[(w * 32 + mt * 16 + li) * 72 + ks * 32 + la * 8];
                accl[mt] = __builtin_amdgcn_mfma_f32_16x16x32_bf16(pf, vones, accl[mt], 0, 0, 0);
                #pragma unroll
                for (int dt = 0; dt < 4; dt++) {
                    const bf16x8 vf = *(const bf16x8*)&vt[(dt * 16 + li) * 72 + ks * 32 + la * 8];
                    accO[mt][dt] = __builtin_amdgcn_mfma_f32_16x16x32_bf16(pf, vf, accO[mt][dt], 0, 0, 0);
                }
            }
        }
    }

    // epilogue: accl rows (m = la*4+r) align with accO rows -> no shuffles
    #pragma unroll
    for (int mt = 0; mt < 2; mt++) {
        float linv[4];
        #pragma unroll
        for (int r = 0; r < 4; r++) linv[r] = 1.f / accl[mt][r];
        #pragma unroll
        for (int dt = 0; dt < 4; dt++)
            #pragma unroll
            for (int r = 0; r < 4; r++) {
                const int row = b * SEQ + i0 + w * 32 + mt * 16 + la * 4 + r;
                ao[(size_t)row * 1024 + h * 64 + dt * 16 + li] = f2bf(accO[mt][dt][r] * linv[r]);
            }
    }
}

extern "C" void kernel_launch(void* const* d_in, const int* in_sizes, int n_in,
                              void* d_out, int out_size, void* d_ws, size_t ws_size,
                              hipStream_t stream) {
    const float* hs = (const float*)d_in[0];
    const float* Wq = (const float*)d_in[1];
    const float* bq = (const float*)d_in[2];
    const float* Wk = (const float*)d_in[3];
    const float* bk = (const float*)d_in[4];
    const float* Wv = (const float*)d_in[5];
    const float* bv = (const float*)d_in[6];
    const float* Wo = (const float*)d_in[7];
    const float* bo = (const float*)d_in[8];

    char* p = (char*)d_ws;                                        // 38 MB total
    unsigned short* hsb = (unsigned short*)(p);                   //  8 MB
    unsigned short* wT  = (unsigned short*)(p + 8388608u);        //  4 MB
    unsigned short* woT = (unsigned short*)(p + 12582912u);       //  2 MB
    float*          ball= (float*)(p + 14680064u);                //  8 KB
    unsigned short* qHb = (unsigned short*)(p + 14688256u);       //  4 MB
    unsigned short* kHb = (unsigned short*)(p + 18882560u);       //  4 MB
    unsigned short* vTb = (unsigned short*)(p + 23076864u);       //  8 MB
    unsigned short* ao  = (unsigned short*)(p + 31465472u);       //  8 MB

    prep_all<<<dim3(2824), 256, 0, stream>>>(hs, Wq, Wk, Wv, Wo, bq, bk, bv,
                                             hsb, wT, woT, ball);

    gemm_qkv<<<dim3(16, 32), 256, 0, stream>>>(hsb, wT, ball, qHb, kHb, vTb);

    attn_v6<<<dim3(512), 256, 0, stream>>>(qHb, kHb, vTb, ao);

    gemm_out<<<dim3(8, 64), 256, 0, stream>>>(ao, woT, bo, (float*)d_out);
}

// Round 11
// 196.208 us; speedup vs baseline: 1.0802x; 1.0123x over previous
//
#include <hip/hip_runtime.h>

#define EMBED   1024
#define NHEADS  16
#define RANK    32
#define HDIM    64
#define BATCH   2
#define SEQ     2048
#define BSQ     (BATCH * SEQ)          // 4096 rows
#define CEXP    0.25505998f            // (1/sqrt(32)) * log2(e)

typedef __attribute__((ext_vector_type(8))) short bf16x8;   // 8 bf16 = 4 VGPRs
typedef __attribute__((ext_vector_type(4))) float f32x4;    // MFMA 16x16 acc

__device__ __forceinline__ float bf2f(unsigned short u) {
    union { unsigned int i; float f; } x; x.i = ((unsigned int)u) << 16;
    return x.f;
}
__device__ __forceinline__ unsigned short f2bf(float f) {
    union { float f; unsigned int i; } x; x.f = f;
    unsigned int r = x.i + 0x7FFFu + ((x.i >> 16) & 1u);    // RNE
    return (unsigned short)(r >> 16);
}

// async 16B/lane global->LDS copy; lptr wave-uniform (lane scatters +lane*16B)
#define ASYNC16(gp, lp) \
    __builtin_amdgcn_global_load_lds( \
        (const __attribute__((address_space(1))) void*)(gp), \
        (__attribute__((address_space(3))) void*)(lp), 16, 0, 0)

// ---------- merged prep: hs cvt + weight transposes + bias concat ----------
__global__ __launch_bounds__(256) void prep_all(
    const float* __restrict__ hs,
    const float* __restrict__ Wq, const float* __restrict__ Wk,
    const float* __restrict__ Wv, const float* __restrict__ Wo,
    const float* __restrict__ bq, const float* __restrict__ bk,
    const float* __restrict__ bv,
    unsigned short* __restrict__ hsb, unsigned short* __restrict__ wT_all,
    unsigned short* __restrict__ woT, float* __restrict__ ball)
{
    __shared__ float L[64][65];
    const int blk = blockIdx.x;
    const int t = threadIdx.x;

    if (blk < 2048) {
        const size_t i = ((size_t)blk * 256 + t) * 8;
        float4 v0 = *(const float4*)(hs + i);
        float4 v1 = *(const float4*)(hs + i + 4);
        ushort4 o0, o1;
        o0.x = f2bf(v0.x); o0.y = f2bf(v0.y); o0.z = f2bf(v0.z); o0.w = f2bf(v0.w);
        o1.x = f2bf(v1.x); o1.y = f2bf(v1.y); o1.z = f2bf(v1.z); o1.w = f2bf(v1.w);
        *(ushort4*)(hsb + i) = o0;
        *(ushort4*)(hsb + i + 4) = o1;
        return;
    }
    if (blk < 2816) {
        int idx = blk - 2048;
        int z, bx, by;
        if (idx < 256) { z = idx >> 7; int r2 = idx & 127; bx = r2 & 7; by = r2 >> 3; }
        else { idx -= 256; z = 2 + (idx >> 8); int r2 = idx & 255; bx = r2 & 15; by = r2 >> 4; }
        const int Nw = (z < 2) ? 512 : 1024;
        const float* W = (z == 0) ? Wq : (z == 1) ? Wk : (z == 2) ? Wv : Wo;
        unsigned short* dst = (z == 3) ? woT : (wT_all + (size_t)z * 512 * 1024);

        const int r = t >> 2, c0 = (t & 3) * 16;
        const float* src = W + (size_t)(by * 64 + r) * Nw + bx * 64 + c0;
        #pragma unroll
        for (int u = 0; u < 4; u++)
            *(float4*)&L[r][c0 + 4 * u] = *(const float4*)(src + 4 * u);
        __syncthreads();
        unsigned short* drow = dst + (size_t)(bx * 64 + r) * 1024 + by * 64 + c0;
        #pragma unroll
        for (int u4 = 0; u4 < 4; u4++) {
            ushort4 o;
            o.x = f2bf(L[c0 + 4 * u4 + 0][r]);
            o.y = f2bf(L[c0 + 4 * u4 + 1][r]);
            o.z = f2bf(L[c0 + 4 * u4 + 2][r]);
            o.w = f2bf(L[c0 + 4 * u4 + 3][r]);
            *(ushort4*)(drow + 4 * u4) = o;
        }
        return;
    }
    {
        const int i = (blk - 2816) * 256 + t;
        ball[i] = (i < 512) ? bq[i] : (i < 1024) ? bk[i - 512] : bv[i - 1024];
    }
}

// ---------- QKV MFMA GEMM: 128x64 tiles, 1024 blocks (4/CU) ----------
// Wave w owns rows [w*32,+32) x all 64 cols: acc 2x4. Epilogue scatters to
// qH[bh][s][32], kH[bh][s][32], vT[bh*64+d][s].
__global__ __launch_bounds__(256) void gemm_qkv(
    const unsigned short* __restrict__ A, const unsigned short* __restrict__ BT,
    const float* __restrict__ bias,
    unsigned short* __restrict__ qH, unsigned short* __restrict__ kH,
    unsigned short* __restrict__ vTout)
{
    __shared__ unsigned short As[128 * 32];   // 8 KB
    __shared__ unsigned short Bs[64 * 32];    // 4 KB
    const int K = 1024;
    const int t = threadIdx.x;
    const int lane = t & 63;
    const int li = lane & 15, la = lane >> 4;
    const int w = t >> 6;
    const int row0 = blockIdx.y * 128, col0 = blockIdx.x * 64;

    const int sr = lane >> 2, sc2 = (lane & 3) * 8;
    const unsigned short* ag0 = A + (size_t)(row0 + w * 32 + sr) * K + sc2;
    const unsigned short* ag1 = A + (size_t)(row0 + w * 32 + 16 + sr) * K + sc2;
    const unsigned short* bg0 = BT + (size_t)(col0 + w * 16 + sr) * K + sc2;
    unsigned short* lA0 = &As[(w * 32) * 32];
    unsigned short* lA1 = &As[(w * 32 + 16) * 32];
    unsigned short* lB0 = &Bs[(w * 16) * 32];

    f32x4 acc[2][4];
    #pragma unroll
    for (int i = 0; i < 2; i++)
        #pragma unroll
        for (int j = 0; j < 4; j++)
            acc[i][j] = (f32x4){0.f, 0.f, 0.f, 0.f};

    for (int k0 = 0; k0 < K; k0 += 32) {
        ASYNC16(ag0 + k0, lA0);
        ASYNC16(ag1 + k0, lA1);
        ASYNC16(bg0 + k0, lB0);
        __syncthreads();
        bf16x8 af[2], bfr[4];
        #pragma unroll
        for (int mt = 0; mt < 2; mt++)
            af[mt] = *(const bf16x8*)&As[(w * 32 + mt * 16 + li) * 32 + la * 8];
        #pragma unroll
        for (int nt = 0; nt < 4; nt++)
            bfr[nt] = *(const bf16x8*)&Bs[(nt * 16 + li) * 32 + la * 8];
        #pragma unroll
        for (int mt = 0; mt < 2; mt++)
            #pragma unroll
            for (int nt = 0; nt < 4; nt++)
                acc[mt][nt] = __builtin_amdgcn_mfma_f32_16x16x32_bf16(af[mt], bfr[nt], acc[mt][nt], 0, 0, 0);
        __syncthreads();
    }

    const int bb = row0 >> 11;               // batch (tile never crosses)
    const int jb = (row0 & 2047) + w * 32;
    #pragma unroll
    for (int nt = 0; nt < 4; nt++) {
        const int col = col0 + nt * 16 + li;
        const float bval = bias[col];
        if (col < 1024) {
            const int hh = (col & 511) >> 5;
            const int rr = col & 31;
            unsigned short* base = ((col < 512) ? qH : kH)
                + ((size_t)(bb * 16 + hh) * 2048) * 32 + rr;
            #pragma unroll
            for (int mt = 0; mt < 2; mt++)
                #pragma unroll
                for (int r = 0; r < 4; r++)
                    base[(size_t)(jb + mt * 16 + la * 4 + r) * 32] =
                        f2bf(acc[mt][nt][r] + bval);
        } else {
            const int hd = col - 1024;
            unsigned short* dcol = vTout + ((size_t)(bb * 16 + (hd >> 6)) * 64 + (hd & 63)) * SEQ;
            #pragma unroll
            for (int mt = 0; mt < 2; mt++) {
                const int srow = jb + mt * 16 + la * 4;
                ushort4 o;
                o.x = f2bf(acc[mt][nt][0] + bval);
                o.y = f2bf(acc[mt][nt][1] + bval);
                o.z = f2bf(acc[mt][nt][2] + bval);
                o.w = f2bf(acc[mt][nt][3] + bval);
                *(ushort4*)(dcol + srow) = o;
            }
        }
    }
}

// ---------- out-proj GEMM: 64x64 tiles, 1024 blocks (4/CU) ----------
__global__ __launch_bounds__(256) void gemm_out(
    const unsigned short* __restrict__ A, const unsigned short* __restrict__ BT,
    const float* __restrict__ bias, float* __restrict__ C)
{
    __shared__ unsigned short As[64 * 32];    // 4 KB
    __shared__ unsigned short Bs[64 * 32];    // 4 KB
    const int K = 1024;
    const int t = threadIdx.x;
    const int lane = t & 63;
    const int li = lane & 15, la = lane >> 4;
    const int w = t >> 6;
    const int row0 = blockIdx.y * 64, col0 = blockIdx.x * 64;

    const int sr = lane >> 2, sc2 = (lane & 3) * 8;
    const unsigned short* ag0 = A + (size_t)(row0 + w * 16 + sr) * K + sc2;
    const unsigned short* bg0 = BT + (size_t)(col0 + w * 16 + sr) * K + sc2;
    unsigned short* lA0 = &As[(w * 16) * 32];
    unsigned short* lB0 = &Bs[(w * 16) * 32];

    f32x4 acc[4];
    #pragma unroll
    for (int j = 0; j < 4; j++) acc[j] = (f32x4){0.f, 0.f, 0.f, 0.f};

    for (int k0 = 0; k0 < K; k0 += 32) {
        ASYNC16(ag0 + k0, lA0);
        ASYNC16(bg0 + k0, lB0);
        __syncthreads();
        bf16x8 af, bfr[4];
        af = *(const bf16x8*)&As[(w * 16 + li) * 32 + la * 8];
        #pragma unroll
        for (int nt = 0; nt < 4; nt++)
            bfr[nt] = *(const bf16x8*)&Bs[(nt * 16 + li) * 32 + la * 8];
        #pragma unroll
        for (int nt = 0; nt < 4; nt++)
            acc[nt] = __builtin_amdgcn_mfma_f32_16x16x32_bf16(af, bfr[nt], acc[nt], 0, 0, 0);
        __syncthreads();
    }

    #pragma unroll
    for (int nt = 0; nt < 4; nt++) {
        const int col = col0 + nt * 16 + li;
        const float bval = bias[col];
        #pragma unroll
        for (int r = 0; r < 4; r++) {
            const int row = row0 + w * 16 + la * 4 + r;
            C[(size_t)row * 1024 + col] = acc[nt][r] + bval;
        }
    }
}

// ---------- MFMA flash attention v7: dbuf K/V, ONE barrier/iter ----------
// 512 blocks (blockIdx = itile*32 + bh). Wave w owns i-rows [i0+w*32,+32).
// Double-buffered kt/vt: barrier at top of each 64-j tile separates prior
// reads from next writes (2-buffer invariant). Prefetch distance 2 tiles.
__global__ __launch_bounds__(256) void attn_v7(
    const unsigned short* __restrict__ qH,
    const unsigned short* __restrict__ kH,
    const unsigned short* __restrict__ vT,
    unsigned short* __restrict__ ao)
{
    __shared__ unsigned short kt[2][64 * 48];   // 12 KB
    __shared__ unsigned short vt[2][64 * 72];   // 18 KB
    __shared__ unsigned short P[128 * 72];      // 18 KB

    const int t = threadIdx.x;
    const int lane = t & 63;
    const int li = lane & 15, la = lane >> 4;
    const int w = t >> 6;

    const int bh = blockIdx.x & 31;
    const int itile = blockIdx.x >> 5;
    const int i0 = itile * 128;
    const int b = bh >> 4, h = bh & 15;

    // 2 Q frags (B-operand), CEXP folded
    bf16x8 qf[2];
    #pragma unroll
    for (int it = 0; it < 2; it++) {
        const unsigned short* qp = qH + ((size_t)bh * 2048 + i0 + w * 32 + it * 16 + li) * 32 + la * 8;
        ushort4 q0 = *(const ushort4*)qp;
        ushort4 q1 = *(const ushort4*)(qp + 4);
        short u[8];
        u[0] = (short)f2bf(bf2f(q0.x) * CEXP);
        u[1] = (short)f2bf(bf2f(q0.y) * CEXP);
        u[2] = (short)f2bf(bf2f(q0.z) * CEXP);
        u[3] = (short)f2bf(bf2f(q0.w) * CEXP);
        u[4] = (short)f2bf(bf2f(q1.x) * CEXP);
        u[5] = (short)f2bf(bf2f(q1.y) * CEXP);
        u[6] = (short)f2bf(bf2f(q1.z) * CEXP);
        u[7] = (short)f2bf(bf2f(q1.w) * CEXP);
        qf[it] = *(const bf16x8*)u;
    }

    bf16x8 vones;
    #pragma unroll
    for (int u2 = 0; u2 < 8; u2++) vones[u2] = (short)0x3F80;   // bf16 1.0

    const int kr = t >> 2, kc = (t & 3) * 8;        // K staging: 64 rows x 64B
    const int vr = t >> 3, vc = (t & 7) * 8;        // V staging: rows d/d+32
    const unsigned short* kp = kH + (size_t)bh * 2048 * 32 + (size_t)kr * 32 + kc;
    const unsigned short* vp0 = vT + (size_t)bh * 64 * SEQ + (size_t)vr * SEQ + vc;
    const unsigned short* vp1 = vp0 + (size_t)32 * SEQ;

    f32x4 accO[2][4], accl[2];
    #pragma unroll
    for (int mt = 0; mt < 2; mt++) {
        accl[mt] = (f32x4){0.f, 0.f, 0.f, 0.f};
        #pragma unroll
        for (int dt = 0; dt < 4; dt++) accO[mt][dt] = (f32x4){0.f, 0.f, 0.f, 0.f};
    }

    // preamble: tile0 -> buf0; load tile1 into regs
    uint4 kreg  = *(const uint4*)(kp);
    uint4 vreg0 = *(const uint4*)(vp0);
    uint4 vreg1 = *(const uint4*)(vp1);
    *(uint4*)&kt[0][kr * 48 + kc] = kreg;
    *(uint4*)&vt[0][vr * 72 + vc] = vreg0;
    *(uint4*)&vt[0][(vr + 32) * 72 + vc] = vreg1;
    kreg  = *(const uint4*)(kp + 64 * 32);
    vreg0 = *(const uint4*)(vp0 + 64);
    vreg1 = *(const uint4*)(vp1 + 64);

    #define ATTN_BODY(BUF, OTHER, JPRE)                                            \
    {                                                                              \
        __syncthreads();                                                           \
        *(uint4*)&kt[OTHER][kr * 48 + kc] = kreg;                                  \
        *(uint4*)&vt[OTHER][vr * 72 + vc] = vreg0;                                 \
        *(uint4*)&vt[OTHER][(vr + 32) * 72 + vc] = vreg1;                          \
        const int jn = (JPRE) & 2047;                                              \
        kreg  = *(const uint4*)(kp + (size_t)jn * 32);                             \
        vreg0 = *(const uint4*)(vp0 + jn);                                         \
        vreg1 = *(const uint4*)(vp1 + jn);                                         \
        f32x4 sc[4][2];                                                            \
        _Pragma("unroll")                                                          \
        for (int jt = 0; jt < 4; jt++) {                                           \
            const bf16x8 kf = *(const bf16x8*)&kt[BUF][(jt * 16 + li) * 48 + la * 8]; \
            sc[jt][0] = __builtin_amdgcn_mfma_f32_16x16x32_bf16(kf, qf[0], (f32x4){0.f,0.f,0.f,0.f}, 0, 0, 0); \
            sc[jt][1] = __builtin_amdgcn_mfma_f32_16x16x32_bf16(kf, qf[1], (f32x4){0.f,0.f,0.f,0.f}, 0, 0, 0); \
        }                                                                          \
        _Pragma("unroll")                                                          \
        for (int jt = 0; jt < 4; jt++)                                             \
            _Pragma("unroll")                                                      \
            for (int it = 0; it < 2; it++) {                                       \
                union { float f; unsigned int u; } c0, c1, c2, c3;                 \
                c0.f = exp2f(sc[jt][it][0]);                                       \
                c1.f = exp2f(sc[jt][it][1]);                                       \
                c2.f = exp2f(sc[jt][it][2]);                                       \
                c3.f = exp2f(sc[jt][it][3]);                                       \
                uint2 pk;                                                          \
                pk.x = __builtin_amdgcn_perm(c1.u + 0x8000u, c0.u + 0x8000u, 0x07060302u); \
                pk.y = __builtin_amdgcn_perm(c3.u + 0x8000u, c2.u + 0x8000u, 0x07060302u); \
                *(uint2*)&P[(w * 32 + it * 16 + li) * 72 + jt * 16 + la * 4] = pk; \
            }                                                                      \
        _Pragma("unroll")                                                          \
        for (int mt = 0; mt < 2; mt++) {                                           \
            _Pragma("unroll")                                                      \
            for (int ks = 0; ks < 2; ks++) {                                       \
                const bf16x8 pf = *(const bf16x8*)&P[(w * 32 + mt * 16 + li) * 72 + ks * 32 + la * 8]; \
                accl[mt] = __builtin_amdgcn_mfma_f32_16x16x32_bf16(pf, vones, accl[mt], 0, 0, 0); \
                _Pragma("unroll")                                                  \
                for (int dt = 0; dt < 4; dt++) {                                   \
                    const bf16x8 vf = *(const bf16x8*)&vt[BUF][(dt * 16 + li) * 72 + ks * 32 + la * 8]; \
                    accO[mt][dt] = __builtin_amdgcn_mfma_f32_16x16x32_bf16(pf, vf, accO[mt][dt], 0, 0, 0); \
                }                                                                  \
            }                                                                      \
        }                                                                          \
    }

    for (int j0 = 0; j0 < SEQ; j0 += 128) {
        ATTN_BODY(0, 1, j0 + 128)
        ATTN_BODY(1, 0, j0 + 192)
    }
    #undef ATTN_BODY

    // epilogue: accl rows align with accO rows -> no shuffles
    #pragma unroll
    for (int mt = 0; mt < 2; mt++) {
        float linv[4];
        #pragma unroll
        for (int r = 0; r < 4; r++) linv[r] = 1.f / accl[mt][r];
        #pragma unroll
        for (int dt = 0; dt < 4; dt++)
            #pragma unroll
            for (int r = 0; r < 4; r++) {
                const int row = b * SEQ + i0 + w * 32 + mt * 16 + la * 4 + r;
                ao[(size_t)row * 1024 + h * 64 + dt * 16 + li] = f2bf(accO[mt][dt][r] * linv[r]);
            }
    }
}

extern "C" void kernel_launch(void* const* d_in, const int* in_sizes, int n_in,
                              void* d_out, int out_size, void* d_ws, size_t ws_size,
                              hipStream_t stream) {
    const float* hs = (const float*)d_in[0];
    const float* Wq = (const float*)d_in[1];
    const float* bq = (const float*)d_in[2];
    const float* Wk = (const float*)d_in[3];
    const float* bk = (const float*)d_in[4];
    const float* Wv = (const float*)d_in[5];
    const float* bv = (const float*)d_in[6];
    const float* Wo = (const float*)d_in[7];
    const float* bo = (const float*)d_in[8];

    char* p = (char*)d_ws;                                        // 38 MB total
    unsigned short* hsb = (unsigned short*)(p);                   //  8 MB
    unsigned short* wT  = (unsigned short*)(p + 8388608u);        //  4 MB
    unsigned short* woT = (unsigned short*)(p + 12582912u);       //  2 MB
    float*          ball= (float*)(p + 14680064u);                //  8 KB
    unsigned short* qHb = (unsigned short*)(p + 14688256u);       //  4 MB
    unsigned short* kHb = (unsigned short*)(p + 18882560u);       //  4 MB
    unsigned short* vTb = (unsigned short*)(p + 23076864u);       //  8 MB
    unsigned short* ao  = (unsigned short*)(p + 31465472u);       //  8 MB

    prep_all<<<dim3(2824), 256, 0, stream>>>(hs, Wq, Wk, Wv, Wo, bq, bk, bv,
                                             hsb, wT, woT, ball);

    gemm_qkv<<<dim3(32, 32), 256, 0, stream>>>(hsb, wT, ball, qHb, kHb, vTb);

    attn_v7<<<dim3(512), 256, 0, stream>>>(qHb, kHb, vTb, ao);

    gemm_out<<<dim3(16, 64), 256, 0, stream>>>(ao, woT, bo, (float*)d_out);
}

// Round 12
// 189.463 us; speedup vs baseline: 1.1186x; 1.0356x over previous
//
#include <hip/hip_runtime.h>

#define EMBED   1024
#define NHEADS  16
#define RANK    32
#define HDIM    64
#define BATCH   2
#define SEQ     2048
#define BSQ     (BATCH * SEQ)          // 4096 rows
#define CEXP    0.25505998f            // (1/sqrt(32)) * log2(e)

typedef __attribute__((ext_vector_type(8))) short bf16x8;   // 8 bf16 = 4 VGPRs
typedef __attribute__((ext_vector_type(4))) float f32x4;    // MFMA 16x16 acc

__device__ __forceinline__ float bf2f(unsigned short u) {
    union { unsigned int i; float f; } x; x.i = ((unsigned int)u) << 16;
    return x.f;
}
__device__ __forceinline__ unsigned short f2bf(float f) {
    union { float f; unsigned int i; } x; x.f = f;
    unsigned int r = x.i + 0x7FFFu + ((x.i >> 16) & 1u);    // RNE
    return (unsigned short)(r >> 16);
}

// async 16B/lane global->LDS copy; lptr wave-uniform (lane scatters +lane*16B)
#define ASYNC16(gp, lp) \
    __builtin_amdgcn_global_load_lds( \
        (const __attribute__((address_space(1))) void*)(gp), \
        (__attribute__((address_space(3))) void*)(lp), 16, 0, 0)

// ---------- merged prep: hs cvt + weight transposes + bias concat ----------
__global__ __launch_bounds__(256) void prep_all(
    const float* __restrict__ hs,
    const float* __restrict__ Wq, const float* __restrict__ Wk,
    const float* __restrict__ Wv, const float* __restrict__ Wo,
    const float* __restrict__ bq, const float* __restrict__ bk,
    const float* __restrict__ bv,
    unsigned short* __restrict__ hsb, unsigned short* __restrict__ wT_all,
    unsigned short* __restrict__ woT, float* __restrict__ ball)
{
    __shared__ float L[64][65];
    const int blk = blockIdx.x;
    const int t = threadIdx.x;

    if (blk < 2048) {
        const size_t i = ((size_t)blk * 256 + t) * 8;
        float4 v0 = *(const float4*)(hs + i);
        float4 v1 = *(const float4*)(hs + i + 4);
        ushort4 o0, o1;
        o0.x = f2bf(v0.x); o0.y = f2bf(v0.y); o0.z = f2bf(v0.z); o0.w = f2bf(v0.w);
        o1.x = f2bf(v1.x); o1.y = f2bf(v1.y); o1.z = f2bf(v1.z); o1.w = f2bf(v1.w);
        *(ushort4*)(hsb + i) = o0;
        *(ushort4*)(hsb + i + 4) = o1;
        return;
    }
    if (blk < 2816) {
        int idx = blk - 2048;
        int z, bx, by;
        if (idx < 256) { z = idx >> 7; int r2 = idx & 127; bx = r2 & 7; by = r2 >> 3; }
        else { idx -= 256; z = 2 + (idx >> 8); int r2 = idx & 255; bx = r2 & 15; by = r2 >> 4; }
        const int Nw = (z < 2) ? 512 : 1024;
        const float* W = (z == 0) ? Wq : (z == 1) ? Wk : (z == 2) ? Wv : Wo;
        unsigned short* dst = (z == 3) ? woT : (wT_all + (size_t)z * 512 * 1024);

        const int r = t >> 2, c0 = (t & 3) * 16;
        const float* src = W + (size_t)(by * 64 + r) * Nw + bx * 64 + c0;
        #pragma unroll
        for (int u = 0; u < 4; u++)
            *(float4*)&L[r][c0 + 4 * u] = *(const float4*)(src + 4 * u);
        __syncthreads();
        unsigned short* drow = dst + (size_t)(bx * 64 + r) * 1024 + by * 64 + c0;
        #pragma unroll
        for (int u4 = 0; u4 < 4; u4++) {
            ushort4 o;
            o.x = f2bf(L[c0 + 4 * u4 + 0][r]);
            o.y = f2bf(L[c0 + 4 * u4 + 1][r]);
            o.z = f2bf(L[c0 + 4 * u4 + 2][r]);
            o.w = f2bf(L[c0 + 4 * u4 + 3][r]);
            *(ushort4*)(drow + 4 * u4) = o;
        }
        return;
    }
    {
        const int i = (blk - 2816) * 256 + t;
        ball[i] = (i < 512) ? bq[i] : (i < 1024) ? bk[i - 512] : bv[i - 1024];
    }
}

// ---------- QKV MFMA GEMM: 128x128 tiles, BK=64 (16 iters, half barriers) ----
// LDS holds two stacked [128][32] half-K sub-tiles (m97-verified geometry).
// Epilogue scatters to qH[bh][s][32], kH[bh][s][32], vT[bh*64+d][s].
__global__ __launch_bounds__(256) void gemm_qkv(
    const unsigned short* __restrict__ A, const unsigned short* __restrict__ BT,
    const float* __restrict__ bias,
    unsigned short* __restrict__ qH, unsigned short* __restrict__ kH,
    unsigned short* __restrict__ vTout)
{
    __shared__ unsigned short As[2 * 128 * 32];   // 16 KB
    __shared__ unsigned short Bs[2 * 128 * 32];   // 16 KB
    const int K = 1024;
    const int t = threadIdx.x;
    const int lane = t & 63;
    const int li = lane & 15, la = lane >> 4;
    const int w = t >> 6, wm = w >> 1, wn = w & 1;
    const int row0 = blockIdx.y * 128, col0 = blockIdx.x * 128;

    const int sr = lane >> 2, sc2 = (lane & 3) * 8;    // 16 rows / instr
    const unsigned short* ag = A + (size_t)(row0 + sr) * K + sc2;
    const unsigned short* bg = BT + (size_t)(col0 + sr) * K + sc2;

    f32x4 acc[4][4];
    #pragma unroll
    for (int i = 0; i < 4; i++)
        #pragma unroll
        for (int j = 0; j < 4; j++)
            acc[i][j] = (f32x4){0.f, 0.f, 0.f, 0.f};

    for (int k0 = 0; k0 < K; k0 += 64) {
        #pragma unroll
        for (int kh = 0; kh < 2; kh++)
            #pragma unroll
            for (int u = 0; u < 2; u++) {
                const int ro = w * 32 + u * 16;
                ASYNC16(ag + (size_t)ro * K + k0 + kh * 32, &As[kh * 4096 + ro * 32]);
                ASYNC16(bg + (size_t)ro * K + k0 + kh * 32, &Bs[kh * 4096 + ro * 32]);
            }
        __syncthreads();
        #pragma unroll
        for (int kh = 0; kh < 2; kh++) {
            bf16x8 af[4], bfr[4];
            #pragma unroll
            for (int mt = 0; mt < 4; mt++)
                af[mt] = *(const bf16x8*)&As[kh * 4096 + (wm * 64 + mt * 16 + li) * 32 + la * 8];
            #pragma unroll
            for (int nt = 0; nt < 4; nt++)
                bfr[nt] = *(const bf16x8*)&Bs[kh * 4096 + (wn * 64 + nt * 16 + li) * 32 + la * 8];
            #pragma unroll
            for (int mt = 0; mt < 4; mt++)
                #pragma unroll
                for (int nt = 0; nt < 4; nt++)
                    acc[mt][nt] = __builtin_amdgcn_mfma_f32_16x16x32_bf16(af[mt], bfr[nt], acc[mt][nt], 0, 0, 0);
        }
        __syncthreads();
    }

    const int bb = row0 >> 11;               // batch (tile never crosses)
    const int jb = (row0 & 2047) + wm * 64;
    #pragma unroll
    for (int nt = 0; nt < 4; nt++) {
        const int col = col0 + wn * 64 + nt * 16 + li;
        const float bval = bias[col];
        if (col < 1024) {
            const int hh = (col & 511) >> 5;
            const int rr = col & 31;
            unsigned short* base = ((col < 512) ? qH : kH)
                + ((size_t)(bb * 16 + hh) * 2048) * 32 + rr;
            #pragma unroll
            for (int mt = 0; mt < 4; mt++)
                #pragma unroll
                for (int r = 0; r < 4; r++)
                    base[(size_t)(jb + mt * 16 + la * 4 + r) * 32] =
                        f2bf(acc[mt][nt][r] + bval);
        } else {
            const int hd = col - 1024;
            unsigned short* dcol = vTout + ((size_t)(bb * 16 + (hd >> 6)) * 64 + (hd & 63)) * SEQ;
            #pragma unroll
            for (int mt = 0; mt < 4; mt++) {
                const int srow = jb + mt * 16 + la * 4;
                ushort4 o;
                o.x = f2bf(acc[mt][nt][0] + bval);
                o.y = f2bf(acc[mt][nt][1] + bval);
                o.z = f2bf(acc[mt][nt][2] + bval);
                o.w = f2bf(acc[mt][nt][3] + bval);
                *(ushort4*)(dcol + srow) = o;
            }
        }
    }
}

// ---------- out-proj GEMM: 64x128 tiles, BK=64 ----------
__global__ __launch_bounds__(256) void gemm_out(
    const unsigned short* __restrict__ A, const unsigned short* __restrict__ BT,
    const float* __restrict__ bias, float* __restrict__ C)
{
    __shared__ unsigned short As[2 * 64 * 32];    // 8 KB
    __shared__ unsigned short Bs[2 * 128 * 32];   // 16 KB
    const int K = 1024;
    const int t = threadIdx.x;
    const int lane = t & 63;
    const int li = lane & 15, la = lane >> 4;
    const int w = t >> 6, wm = w >> 1, wn = w & 1;
    const int row0 = blockIdx.y * 64, col0 = blockIdx.x * 128;

    const int sr = lane >> 2, sc2 = (lane & 3) * 8;
    const unsigned short* ag = A + (size_t)(row0 + sr) * K + sc2;
    const unsigned short* bg = BT + (size_t)(col0 + sr) * K + sc2;

    f32x4 acc[2][4];
    #pragma unroll
    for (int i = 0; i < 2; i++)
        #pragma unroll
        for (int j = 0; j < 4; j++)
            acc[i][j] = (f32x4){0.f, 0.f, 0.f, 0.f};

    for (int k0 = 0; k0 < K; k0 += 64) {
        #pragma unroll
        for (int kh = 0; kh < 2; kh++) {
            // A: 64 rows -> wave w stages rows w*16..+15 per kh
            ASYNC16(ag + (size_t)(w * 16) * K + k0 + kh * 32, &As[kh * 2048 + (w * 16) * 32]);
            // B: 128 rows -> wave w stages rows w*32+u*16
            #pragma unroll
            for (int u = 0; u < 2; u++) {
                const int ro = w * 32 + u * 16;
                ASYNC16(bg + (size_t)ro * K + k0 + kh * 32, &Bs[kh * 4096 + ro * 32]);
            }
        }
        __syncthreads();
        #pragma unroll
        for (int kh = 0; kh < 2; kh++) {
            bf16x8 af[2], bfr[4];
            #pragma unroll
            for (int mt = 0; mt < 2; mt++)
                af[mt] = *(const bf16x8*)&As[kh * 2048 + (wm * 32 + mt * 16 + li) * 32 + la * 8];
            #pragma unroll
            for (int nt = 0; nt < 4; nt++)
                bfr[nt] = *(const bf16x8*)&Bs[kh * 4096 + (wn * 64 + nt * 16 + li) * 32 + la * 8];
            #pragma unroll
            for (int mt = 0; mt < 2; mt++)
                #pragma unroll
                for (int nt = 0; nt < 4; nt++)
                    acc[mt][nt] = __builtin_amdgcn_mfma_f32_16x16x32_bf16(af[mt], bfr[nt], acc[mt][nt], 0, 0, 0);
        }
        __syncthreads();
    }

    #pragma unroll
    for (int nt = 0; nt < 4; nt++) {
        const int col = col0 + wn * 64 + nt * 16 + li;
        const float bval = bias[col];
        #pragma unroll
        for (int mt = 0; mt < 2; mt++)
            #pragma unroll
            for (int r = 0; r < 4; r++) {
                const int row = row0 + wm * 32 + mt * 16 + la * 4 + r;
                C[(size_t)row * 1024 + col] = acc[mt][nt][r] + bval;
            }
    }
}

// ---------- MFMA flash attention v8: i-tile 64, dbuf, 1024 blocks ----------
// blockIdx = itile*32 + bh (all blocks of a head share an XCD: bh mod 8
// invariant under +32). Wave w owns i-rows [i0+w*16,+16). LDS 39 KB ->
// 4 blocks/CU = 4 waves/SIMD (2x v7 occupancy). One barrier per 64-j tile.
__global__ __launch_bounds__(256) void attn_v8(
    const unsigned short* __restrict__ qH,
    const unsigned short* __restrict__ kH,
    const unsigned short* __restrict__ vT,
    unsigned short* __restrict__ ao)
{
    __shared__ unsigned short kt[2][64 * 48];   // 12 KB
    __shared__ unsigned short vt[2][64 * 72];   // 18 KB
    __shared__ unsigned short P[64 * 72];       //  9 KB

    const int t = threadIdx.x;
    const int lane = t & 63;
    const int li = lane & 15, la = lane >> 4;
    const int w = t >> 6;

    const int bh = blockIdx.x & 31;
    const int itile = blockIdx.x >> 5;
    const int i0 = itile * 64;
    const int b = bh >> 4, h = bh & 15;

    // Q frag (B-operand: n=i=w*16+li, k=la*8..+7), CEXP folded
    bf16x8 qf;
    {
        const unsigned short* qp = qH + ((size_t)bh * 2048 + i0 + w * 16 + li) * 32 + la * 8;
        ushort4 q0 = *(const ushort4*)qp;
        ushort4 q1 = *(const ushort4*)(qp + 4);
        short u[8];
        u[0] = (short)f2bf(bf2f(q0.x) * CEXP);
        u[1] = (short)f2bf(bf2f(q0.y) * CEXP);
        u[2] = (short)f2bf(bf2f(q0.z) * CEXP);
        u[3] = (short)f2bf(bf2f(q0.w) * CEXP);
        u[4] = (short)f2bf(bf2f(q1.x) * CEXP);
        u[5] = (short)f2bf(bf2f(q1.y) * CEXP);
        u[6] = (short)f2bf(bf2f(q1.z) * CEXP);
        u[7] = (short)f2bf(bf2f(q1.w) * CEXP);
        qf = *(const bf16x8*)u;
    }

    bf16x8 vones;
    #pragma unroll
    for (int u2 = 0; u2 < 8; u2++) vones[u2] = (short)0x3F80;   // bf16 1.0

    const int kr = t >> 2, kc = (t & 3) * 8;        // K staging: 64 rows x 64B
    const int vr = t >> 3, vc = (t & 7) * 8;        // V staging: rows d/d+32
    const unsigned short* kp = kH + (size_t)bh * 2048 * 32 + (size_t)kr * 32 + kc;
    const unsigned short* vp0 = vT + (size_t)bh * 64 * SEQ + (size_t)vr * SEQ + vc;
    const unsigned short* vp1 = vp0 + (size_t)32 * SEQ;

    f32x4 accO[4], accl;
    accl = (f32x4){0.f, 0.f, 0.f, 0.f};
    #pragma unroll
    for (int dt = 0; dt < 4; dt++) accO[dt] = (f32x4){0.f, 0.f, 0.f, 0.f};
    const int prow = w * 16 + li;

    // preamble: tile0 -> buf0; load tile1 into regs
    uint4 kreg  = *(const uint4*)(kp);
    uint4 vreg0 = *(const uint4*)(vp0);
    uint4 vreg1 = *(const uint4*)(vp1);
    *(uint4*)&kt[0][kr * 48 + kc] = kreg;
    *(uint4*)&vt[0][vr * 72 + vc] = vreg0;
    *(uint4*)&vt[0][(vr + 32) * 72 + vc] = vreg1;
    kreg  = *(const uint4*)(kp + 64 * 32);
    vreg0 = *(const uint4*)(vp0 + 64);
    vreg1 = *(const uint4*)(vp1 + 64);

    #define ATTN_BODY(BUF, OTHER, JPRE)                                            \
    {                                                                              \
        __syncthreads();                                                           \
        *(uint4*)&kt[OTHER][kr * 48 + kc] = kreg;                                  \
        *(uint4*)&vt[OTHER][vr * 72 + vc] = vreg0;                                 \
        *(uint4*)&vt[OTHER][(vr + 32) * 72 + vc] = vreg1;                          \
        const int jn = (JPRE) & 2047;                                              \
        kreg  = *(const uint4*)(kp + (size_t)jn * 32);                             \
        vreg0 = *(const uint4*)(vp0 + jn);                                         \
        vreg1 = *(const uint4*)(vp1 + jn);                                         \
        f32x4 sc[4];                                                               \
        _Pragma("unroll")                                                          \
        for (int jt = 0; jt < 4; jt++) {                                           \
            const bf16x8 kf = *(const bf16x8*)&kt[BUF][(jt * 16 + li) * 48 + la * 8]; \
            sc[jt] = __builtin_amdgcn_mfma_f32_16x16x32_bf16(kf, qf, (f32x4){0.f,0.f,0.f,0.f}, 0, 0, 0); \
        }                                                                          \
        _Pragma("unroll")                                                          \
        for (int jt = 0; jt < 4; jt++) {                                           \
            union { float f; unsigned int u; } c0, c1, c2, c3;                     \
            c0.f = exp2f(sc[jt][0]);                                               \
            c1.f = exp2f(sc[jt][1]);                                               \
            c2.f = exp2f(sc[jt][2]);                                               \
            c3.f = exp2f(sc[jt][3]);                                               \
            uint2 pk;                                                              \
            pk.x = __builtin_amdgcn_perm(c1.u + 0x8000u, c0.u + 0x8000u, 0x07060302u); \
            pk.y = __builtin_amdgcn_perm(c3.u + 0x8000u, c2.u + 0x8000u, 0x07060302u); \
            *(uint2*)&P[prow * 72 + jt * 16 + la * 4] = pk;                        \
        }                                                                          \
        _Pragma("unroll")                                                          \
        for (int ks = 0; ks < 2; ks++) {                                           \
            const bf16x8 pf = *(const bf16x8*)&P[prow * 72 + ks * 32 + la * 8];    \
            accl = __builtin_amdgcn_mfma_f32_16x16x32_bf16(pf, vones, accl, 0, 0, 0); \
            _Pragma("unroll")                                                      \
            for (int dt = 0; dt < 4; dt++) {                                       \
                const bf16x8 vf = *(const bf16x8*)&vt[BUF][(dt * 16 + li) * 72 + ks * 32 + la * 8]; \
                accO[dt] = __builtin_amdgcn_mfma_f32_16x16x32_bf16(pf, vf, accO[dt], 0, 0, 0); \
            }                                                                      \
        }                                                                          \
    }

    for (int j0 = 0; j0 < SEQ; j0 += 128) {
        ATTN_BODY(0, 1, j0 + 128)
        ATTN_BODY(1, 0, j0 + 192)
    }
    #undef ATTN_BODY

    // epilogue: accl rows (m = la*4+r) align with accO rows -> no shuffles
    float linv[4];
    #pragma unroll
    for (int r = 0; r < 4; r++) linv[r] = 1.f / accl[r];
    #pragma unroll
    for (int dt = 0; dt < 4; dt++)
        #pragma unroll
        for (int r = 0; r < 4; r++) {
            const int row = b * SEQ + i0 + w * 16 + la * 4 + r;
            ao[(size_t)row * 1024 + h * 64 + dt * 16 + li] = f2bf(accO[dt][r] * linv[r]);
        }
}

extern "C" void kernel_launch(void* const* d_in, const int* in_sizes, int n_in,
                              void* d_out, int out_size, void* d_ws, size_t ws_size,
                              hipStream_t stream) {
    const float* hs = (const float*)d_in[0];
    const float* Wq = (const float*)d_in[1];
    const float* bq = (const float*)d_in[2];
    const float* Wk = (const float*)d_in[3];
    const float* bk = (const float*)d_in[4];
    const float* Wv = (const float*)d_in[5];
    const float* bv = (const float*)d_in[6];
    const float* Wo = (const float*)d_in[7];
    const float* bo = (const float*)d_in[8];

    char* p = (char*)d_ws;                                        // 38 MB total
    unsigned short* hsb = (unsigned short*)(p);                   //  8 MB
    unsigned short* wT  = (unsigned short*)(p + 8388608u);        //  4 MB
    unsigned short* woT = (unsigned short*)(p + 12582912u);       //  2 MB
    float*          ball= (float*)(p + 14680064u);                //  8 KB
    unsigned short* qHb = (unsigned short*)(p + 14688256u);       //  4 MB
    unsigned short* kHb = (unsigned short*)(p + 18882560u);       //  4 MB
    unsigned short* vTb = (unsigned short*)(p + 23076864u);       //  8 MB
    unsigned short* ao  = (unsigned short*)(p + 31465472u);       //  8 MB

    prep_all<<<dim3(2824), 256, 0, stream>>>(hs, Wq, Wk, Wv, Wo, bq, bk, bv,
                                             hsb, wT, woT, ball);

    gemm_qkv<<<dim3(16, 32), 256, 0, stream>>>(hsb, wT, ball, qHb, kHb, vTb);

    attn_v8<<<dim3(1024), 256, 0, stream>>>(qHb, kHb, vTb, ao);

    gemm_out<<<dim3(8, 64), 256, 0, stream>>>(ao, woT, bo, (float*)d_out);
}